// Round 15
// baseline (43.650 us; speedup 1.0000x reference)
//
#include <hip/hip_runtime.h>
#include <math.h>

#define Tn 2048
#define Cn 1024
#define Hn 64

using u16 = unsigned short;
using u32 = unsigned int;
typedef float f32x4 __attribute__((ext_vector_type(4)));
typedef __bf16 bf16x8 __attribute__((ext_vector_type(8)));
typedef u16 u16x8 __attribute__((ext_vector_type(8)));
typedef u32 u32x4 __attribute__((ext_vector_type(4)));

__device__ __forceinline__ u16 f2bf(float f) {
    return __builtin_bit_cast(u16, static_cast<__bf16>(f));
}

// ---------------------------------------------------------------------------
// W pack: [Wk|Wq|Wv] f32 -> bf16 in MFMA B-fragment order (unchanged).
// ---------------------------------------------------------------------------
__global__ __launch_bounds__(256) void wpack_kernel(
    const float* __restrict__ Wk, const float* __restrict__ Wq,
    const float* __restrict__ Wv, u16* __restrict__ wp)
{
    int slot = blockIdx.x * 256 + threadIdx.x;   // 0..24575
    int n16  = slot >> 11;
    int rem  = slot & 2047;
    int kc   = rem >> 6;
    int lane = rem & 63;
    int l15 = lane & 15, lg = lane >> 4;
    int col = n16 * 16 + l15;                    // 0..191
    const float* __restrict__ Wm = (col < 64) ? Wk : (col < 128) ? Wq : Wv;
    float sc = (col >= 64 && col < 128) ? 0.03125f : 1.0f;
    const float* src = &Wm[(size_t)(col & 63) * Cn + kc * 32 + lg * 8];
    float4 lo = *reinterpret_cast<const float4*>(src);
    float4 hi = *reinterpret_cast<const float4*>(src + 4);
    u16x8 o;
    o[0] = f2bf(lo.x * sc); o[1] = f2bf(lo.y * sc);
    o[2] = f2bf(lo.z * sc); o[3] = f2bf(lo.w * sc);
    o[4] = f2bf(hi.x * sc); o[5] = f2bf(hi.y * sc);
    o[6] = f2bf(hi.z * sc); o[7] = f2bf(hi.w * sc);
    *reinterpret_cast<u16x8*>(&wp[(size_t)slot * 8]) = o;
}

// ---------------------------------------------------------------------------
// QKV projection: R14-exact (BM=32, 256 threads, 2 blocks/CU).
// ---------------------------------------------------------------------------
__global__ __launch_bounds__(256) void qkv_proj(
    const float* __restrict__ x, const u16* __restrict__ wp,
    u16* __restrict__ kb, u16* __restrict__ qb, u16* __restrict__ vb)
{
    __shared__ float xs[2][32 * 68];

    const int tid  = threadIdx.x;
    const int lane = tid & 63;
    const int w    = tid >> 6;        // 0..3
    const int rg   = w & 1;           // rowgroup of 16
    const int cg   = w >> 1;          // colgroup of 96 (6 tiles)
    const int l15  = lane & 15;
    const int lg   = lane >> 4;

    const int row0 = blockIdx.x * 32;
    const int sr   = tid >> 4;          // 0..15
    const int scc  = (tid & 15) << 2;

    f32x4 acc[6];
#pragma unroll
    for (int nt = 0; nt < 6; ++nt)
#pragma unroll
        for (int r = 0; r < 4; ++r) acc[nt][r] = 0.f;

    const float* __restrict__ xsrc0 = &x[(size_t)(row0 + sr) * Cn + scc];
    const float* __restrict__ xsrc1 = &x[(size_t)(row0 + sr + 16) * Cn + scc];
    const u16* __restrict__ wbase = wp + (size_t)cg * 6 * 32 * 64 * 8;

    float4 ga = *reinterpret_cast<const float4*>(xsrc0);
    float4 gb = *reinterpret_cast<const float4*>(xsrc1);
    *reinterpret_cast<float4*>(&xs[0][sr * 68 + scc]) = ga;
    *reinterpret_cast<float4*>(&xs[0][(sr + 16) * 68 + scc]) = gb;
    __syncthreads();

    for (int ks = 0; ks < 16; ++ks) {
        const int cur = ks & 1;
        if (ks < 15) {
            ga = *reinterpret_cast<const float4*>(xsrc0 + (ks + 1) * 64);
            gb = *reinterpret_cast<const float4*>(xsrc1 + (ks + 1) * 64);
        }
#pragma unroll
        for (int kc2 = 0; kc2 < 2; ++kc2) {
            const float* ap = &xs[cur][(rg * 16 + l15) * 68 + kc2 * 32 + (lg << 3)];
            f32x4 a0 = *reinterpret_cast<const f32x4*>(ap);
            f32x4 a1 = *reinterpret_cast<const f32x4*>(ap + 4);
            bf16x8 a;
            a[0] = (__bf16)a0[0]; a[1] = (__bf16)a0[1];
            a[2] = (__bf16)a0[2]; a[3] = (__bf16)a0[3];
            a[4] = (__bf16)a1[0]; a[5] = (__bf16)a1[1];
            a[6] = (__bf16)a1[2]; a[7] = (__bf16)a1[3];
            const int kcg = ks * 2 + kc2;
#pragma unroll
            for (int nt = 0; nt < 6; ++nt) {
                bf16x8 bfr = *reinterpret_cast<const bf16x8*>(
                    &wbase[(size_t)((nt * 32 + kcg) * 64 + lane) * 8]);
                acc[nt] = __builtin_amdgcn_mfma_f32_16x16x32_bf16(a, bfr, acc[nt], 0, 0, 0);
            }
        }
        if (ks < 15) {
            *reinterpret_cast<float4*>(&xs[cur ^ 1][sr * 68 + scc]) = ga;
            *reinterpret_cast<float4*>(&xs[cur ^ 1][(sr + 16) * 68 + scc]) = gb;
        }
        __syncthreads();
    }

#pragma unroll
    for (int nt = 0; nt < 6; ++nt) {
        const int col0 = cg * 96 + nt * 16;
        const int mat  = col0 >> 6;
        u16* __restrict__ ob = (mat == 0) ? kb : (mat == 1) ? qb : vb;
        const int h = (col0 & 63) + l15;
#pragma unroll
        for (int reg = 0; reg < 4; ++reg) {
            const int grow = row0 + rg * 16 + (lg << 2) + reg;
            ob[(size_t)grow * Hn + h] = f2bf(acc[nt][reg]);
        }
    }
}

// ---------------------------------------------------------------------------
// Causal flash attention, split-KV 512-key chunks, PAIRED QTILES:
// qtiles 2qp and 2qp+1 have identical tile counts -> one 512-thread block
// (8 waves = qtile-half x rowgroup x parity) computes both over ONE staged
// K/V chunk.  Staging traffic/instructions halve; 320 blocks.
// Swapped QK^T softmax (R13).  LDS: Ks+VTs 36.9KB; merge slab reuses it.
// ---------------------------------------------------------------------------
__global__ __launch_bounds__(512) void attn(
    const u16* __restrict__ qb, const u16* __restrict__ kb,
    const u16* __restrict__ vb, float* __restrict__ Opart,
    float* __restrict__ mlb, float* __restrict__ out)
{
    __shared__ u16 sm[18432];            // Ks [2][64*72] | VTs [2][64*72]
    u16* Ks  = sm;                       // [2][4608]
    u16* VTs = sm + 9216;

    const int tid  = threadIdx.x;
    const int lane = tid & 63;
    const int w    = tid >> 6;           // 0..7
    const int qh   = w >> 2;             // qtile half 0/1
    const int g    = (w >> 1) & 1;       // rowgroup 0/1
    const int p    = w & 1;              // key parity
    const int l15  = lane & 15;
    const int lg   = lane >> 4;

    // decode (b, qp, c): per batch 80 blocks; gq group = qp>>3 has
    // 8 pairs x (gq+1) chunks; starts 0,8,24,48.
    const int bid = blockIdx.x;
    const int b = bid / 80;
    const int r = bid % 80;
    int gq, qp, c;
    if (r < 8)       { gq = 0; qp = r;                 c = 0;            }
    else if (r < 24) { gq = 1; qp = 8 + (r - 8) / 2;   c = (r - 8) % 2;  }
    else if (r < 48) { gq = 2; qp = 16 + (r - 24) / 3; c = (r - 24) % 3; }
    else             { gq = 3; qp = 24 + (r - 48) / 4; c = (r - 48) % 4; }
    const int qt  = 2 * qp + qh;
    const int c8  = c * 8;

    const int wr0 = qt * 32 + g * 16;
    const int nkt = qp + 1;
    const int rounds = (nkt - c8 + 1) >> 1 < 4 ? (nkt - c8 + 1) >> 1 : 4;
    const size_t kvbase = (size_t)b * Tn * Hn;

    bf16x8 qf[2];
    {
        const u16* qrow = qb + ((size_t)(b * Tn + wr0 + l15)) * Hn;
        qf[0] = *reinterpret_cast<const bf16x8*>(&qrow[(lg << 3)]);
        qf[1] = *reinterpret_cast<const bf16x8*>(&qrow[32 + (lg << 3)]);
    }

    f32x4 o[4];
    float m = -INFINITY, ls = 0.f;
#pragma unroll
    for (int nt = 0; nt < 4; ++nt)
#pragma unroll
        for (int rg2 = 0; rg2 < 4; ++rg2) o[nt][rg2] = 0.f;

    const int srcA = l15 + ((lane >> 4) & 1) * 32;
    const int srcB = srcA + 16;
    const bool hiSel = ((lg >> 1) & 1) != 0;

    // staging coords (512 threads; each covers one chunk per tile)
    const int krow = tid >> 3, kcb = (tid & 7) << 3;   // K: 64 rows x 8 octets
    const int vk = tid & 63, vd0 = (tid >> 6) << 3;    // V: 64 k x 8 d-groups

    for (int s = 0; s < rounds; ++s) {
        const int kt0 = c8 + 2 * s, kt1 = kt0 + 1;
        {
            *reinterpret_cast<u16x8*>(&Ks[0 * 4608 + krow * 72 + kcb]) =
                *reinterpret_cast<const u16x8*>(&kb[kvbase + (size_t)(kt0 * 64 + krow) * Hn + kcb]);
            u16x8 v = *reinterpret_cast<const u16x8*>(&vb[kvbase + (size_t)(kt0 * 64 + vk) * Hn + vd0]);
#pragma unroll
            for (int j = 0; j < 8; ++j) VTs[0 * 4608 + (vd0 + j) * 72 + vk] = v[j];
        }
        if (kt1 < nkt) {
            *reinterpret_cast<u16x8*>(&Ks[1 * 4608 + krow * 72 + kcb]) =
                *reinterpret_cast<const u16x8*>(&kb[kvbase + (size_t)(kt1 * 64 + krow) * Hn + kcb]);
            u16x8 v = *reinterpret_cast<const u16x8*>(&vb[kvbase + (size_t)(kt1 * 64 + vk) * Hn + vd0]);
#pragma unroll
            for (int j = 0; j < 8; ++j) VTs[1 * 4608 + (vd0 + j) * 72 + vk] = v[j];
        }
        __syncthreads();

        const int mykt = kt0 + p;
        if (mykt < nkt) {
            f32x4 sf[4];
#pragma unroll
            for (int nt = 0; nt < 4; ++nt)
#pragma unroll
                for (int rg2 = 0; rg2 < 4; ++rg2) sf[nt][rg2] = 0.f;
#pragma unroll
            for (int kc = 0; kc < 2; ++kc) {
#pragma unroll
                for (int nt = 0; nt < 4; ++nt) {
                    bf16x8 kf = *reinterpret_cast<const bf16x8*>(
                        &Ks[p * 4608 + (nt * 16 + l15) * 72 + kc * 32 + (lg << 3)]);
                    sf[nt] = __builtin_amdgcn_mfma_f32_16x16x32_bf16(kf, qf[kc], sf[nt], 0, 0, 0);
                }
            }
            if (mykt * 64 + 63 > wr0) {
                const int tq = wr0 + l15;
#pragma unroll
                for (int nt = 0; nt < 4; ++nt) {
#pragma unroll
                    for (int reg = 0; reg < 4; ++reg) {
                        int kg = mykt * 64 + nt * 16 + (lg << 2) + reg;
                        if (kg > tq) sf[nt][reg] = -INFINITY;
                    }
                }
            }
            float tm = sf[0][0];
#pragma unroll
            for (int nt = 0; nt < 4; ++nt)
#pragma unroll
                for (int reg = 0; reg < 4; ++reg) tm = fmaxf(tm, sf[nt][reg]);
            tm = fmaxf(tm, __shfl_xor(tm, 16, 64));
            tm = fmaxf(tm, __shfl_xor(tm, 32, 64));
            if (!__all((tm <= m + 8.f) ? 1 : 0)) {
                float nm = fmaxf(m, tm);
                float al = __expf(m - nm);
                ls *= al;
                float alo[4];
#pragma unroll
                for (int reg = 0; reg < 4; ++reg)
                    alo[reg] = __shfl(al, (lg << 2) | reg, 64);
#pragma unroll
                for (int nt = 0; nt < 4; ++nt)
#pragma unroll
                    for (int reg = 0; reg < 4; ++reg) o[nt][reg] *= alo[reg];
                m = nm;
            }
            float pvv[4][4];
            float rs = 0.f;
#pragma unroll
            for (int nt = 0; nt < 4; ++nt)
#pragma unroll
                for (int reg = 0; reg < 4; ++reg) {
                    pvv[nt][reg] = __expf(sf[nt][reg] - m);
                    rs += pvv[nt][reg];
                }
            rs += __shfl_xor(rs, 16, 64);
            rs += __shfl_xor(rs, 32, 64);
            ls += rs;
            u32 wv[4][2];
#pragma unroll
            for (int nt = 0; nt < 4; ++nt)
#pragma unroll
                for (int h = 0; h < 2; ++h)
                    wv[nt][h] = (u32)f2bf(pvv[nt][2 * h]) |
                                ((u32)f2bf(pvv[nt][2 * h + 1]) << 16);
            bf16x8 pa[2];
#pragma unroll
            for (int kc = 0; kc < 2; ++kc) {
                u32 a0 = __shfl(wv[kc * 2][0], srcA, 64);
                u32 b0 = __shfl(wv[kc * 2 + 1][0], srcA, 64);
                u32 a1 = __shfl(wv[kc * 2][1], srcA, 64);
                u32 b1 = __shfl(wv[kc * 2 + 1][1], srcA, 64);
                u32 a2 = __shfl(wv[kc * 2][0], srcB, 64);
                u32 b2 = __shfl(wv[kc * 2 + 1][0], srcB, 64);
                u32 a3 = __shfl(wv[kc * 2][1], srcB, 64);
                u32 b3 = __shfl(wv[kc * 2 + 1][1], srcB, 64);
                u32x4 pw;
                pw[0] = hiSel ? b0 : a0;
                pw[1] = hiSel ? b1 : a1;
                pw[2] = hiSel ? b2 : a2;
                pw[3] = hiSel ? b3 : a3;
                pa[kc] = __builtin_bit_cast(bf16x8, pw);
            }
#pragma unroll
            for (int kc = 0; kc < 2; ++kc) {
#pragma unroll
                for (int nt = 0; nt < 4; ++nt) {
                    bf16x8 vf = *reinterpret_cast<const bf16x8*>(
                        &VTs[p * 4608 + (nt * 16 + l15) * 72 + kc * 32 + (lg << 3)]);
                    o[nt] = __builtin_amdgcn_mfma_f32_16x16x32_bf16(pa[kc], vf, o[nt], 0, 0, 0);
                }
            }
        }
        __syncthreads();
    }

    // parity merge: slab[qh][g] in sm (24.6KB <= 36.9KB)
    float* slab = reinterpret_cast<float*>(sm);
    float* sb = slab + (qh * 2 + g) * (24 * 64);
    if (p == 1) {
#pragma unroll
        for (int nt = 0; nt < 4; ++nt)
#pragma unroll
            for (int reg = 0; reg < 4; ++reg)
                sb[(nt * 4 + reg) * 64 + lane] = o[nt][reg];
        if (lane < 16) {
            sb[1024 + lane] = m;
            sb[1040 + lane] = ls;
        }
    }
    __syncthreads();
    if (p == 0) {
        float mA[4], lA[4], mB[4], lB[4];
#pragma unroll
        for (int reg = 0; reg < 4; ++reg) {
            int q = (lg << 2) | reg;
            mA[reg] = __shfl(m, q, 64);
            lA[reg] = __shfl(ls, q, 64);
            mB[reg] = sb[1024 + q];
            lB[reg] = sb[1040 + q];
        }
        if (gq == 0) {
#pragma unroll
            for (int reg = 0; reg < 4; ++reg) {
                float ms = fmaxf(mA[reg], mB[reg]);
                float aA = __expf(mA[reg] - ms);
                float aB = __expf(mB[reg] - ms);
                float inv = 1.0f / (aA * lA[reg] + aB * lB[reg]);
                int grow = wr0 + (lg << 2) + reg;
                float* orow = out + ((size_t)(b * Tn) + grow) * Hn;
#pragma unroll
                for (int nt = 0; nt < 4; ++nt)
                    orow[nt * 16 + l15] =
                        (aA * o[nt][reg] + aB * sb[(nt * 4 + reg) * 64 + lane]) * inv;
            }
        } else {
            const size_t pidx = (size_t)(b * 64 + qt) * 4 + c;
            float* __restrict__ ob = Opart + pidx * 2048;
#pragma unroll
            for (int reg = 0; reg < 4; ++reg) {
                float ms = fmaxf(mA[reg], mB[reg]);
                float aA = __expf(mA[reg] - ms);
                float aB = __expf(mB[reg] - ms);
                int row32 = g * 16 + (lg << 2) + reg;
                if (l15 == 0) {
                    float* mlp = mlb + pidx * 64 + row32 * 2;
                    mlp[0] = ms;
                    mlp[1] = aA * lA[reg] + aB * lB[reg];
                }
#pragma unroll
                for (int nt = 0; nt < 4; ++nt)
                    ob[row32 * 64 + nt * 16 + l15] =
                        aA * o[nt][reg] + aB * sb[(nt * 4 + reg) * 64 + lane];
            }
        }
    }
}

// ---------------------------------------------------------------------------
// Combine KV-chunk partials (qt >= 16 only; <=4 chunks).  grid 192.
// ---------------------------------------------------------------------------
__global__ __launch_bounds__(256) void attn_merge(
    const float* __restrict__ Opart, const float* __restrict__ mlb,
    float* __restrict__ out)
{
    const int bid = blockIdx.x;
    const int b  = bid / 48;
    const int qt = 16 + bid % 48;
    const int nch = (qt >> 4) + 1;               // 2..4
    const int t = threadIdx.x;
    const int row = t >> 3, d0 = (t & 7) << 3;
    const size_t pbase = (size_t)(b * 64 + qt) * 4;

    float mc[4], lc[4];
#pragma unroll
    for (int cc = 0; cc < 4; ++cc) {
        if (cc < nch) {
            const float* mlp = mlb + (pbase + cc) * 64 + row * 2;
            mc[cc] = mlp[0];
            lc[cc] = mlp[1];
        } else { mc[cc] = -INFINITY; lc[cc] = 0.f; }
    }
    float mfin = fmaxf(fmaxf(mc[0], mc[1]), fmaxf(mc[2], mc[3]));

    float wgt[4], l = 0.f;
#pragma unroll
    for (int cc = 0; cc < 4; ++cc) {
        wgt[cc] = (cc < nch) ? __expf(mc[cc] - mfin) : 0.f;
        l += lc[cc] * wgt[cc];
    }

    f32x4 O0 = {0.f, 0.f, 0.f, 0.f}, O1 = {0.f, 0.f, 0.f, 0.f};
#pragma unroll
    for (int cc = 0; cc < 4; ++cc) {
        if (cc < nch) {
            const float* op = Opart + (pbase + cc) * 2048 + row * 64 + d0;
            f32x4 c0 = *reinterpret_cast<const f32x4*>(op);
            f32x4 c1 = *reinterpret_cast<const f32x4*>(op + 4);
            O0 += c0 * wgt[cc];
            O1 += c1 * wgt[cc];
        }
    }
    float inv = 1.f / l;
    float* orow = out + ((size_t)(b * Tn + qt * 32 + row)) * Hn + d0;
    *reinterpret_cast<f32x4*>(orow)     = O0 * inv;
    *reinterpret_cast<f32x4*>(orow + 4) = O1 * inv;
}

extern "C" void kernel_launch(void* const* d_in, const int* in_sizes, int n_in,
                              void* d_out, int out_size, void* d_ws, size_t ws_size,
                              hipStream_t stream) {
    const float* x  = (const float*)d_in[0];
    const float* Wk = (const float*)d_in[1];
    const float* Wq = (const float*)d_in[2];
    const float* Wv = (const float*)d_in[3];
    float* out = (float*)d_out;

    const size_t rows = (size_t)4 * Tn;            // 8192
    u16* kbuf = (u16*)d_ws;                        // [8192][64] bf16
    u16* qbuf = kbuf + rows * Hn;
    u16* vbuf = qbuf + rows * Hn;
    u16* wpk  = vbuf + rows * Hn;                  // 196608 u16
    float* Opart = (float*)(wpk + 196608);         // [256][4][32][64] f32
    float* mlb   = Opart + (size_t)256 * 4 * 2048; // [256][4][32][2] f32

    wpack_kernel<<<96, 256, 0, stream>>>(Wk, Wq, Wv, wpk);
    qkv_proj<<<256, 256, 0, stream>>>(x, wpk, kbuf, qbuf, vbuf);
    attn<<<320, 512, 0, stream>>>(qbuf, kbuf, vbuf, Opart, mlb, out);
    attn_merge<<<192, 256, 0, stream>>>(Opart, mlb, out);
}

// Round 16
// 42.131 us; speedup vs baseline: 1.0361x; 1.0361x over previous
//
#include <hip/hip_runtime.h>
#include <math.h>

#define Tn 2048
#define Cn 1024
#define Hn 64

using u16 = unsigned short;
using u32 = unsigned int;
typedef float f32x4 __attribute__((ext_vector_type(4)));
typedef __bf16 bf16x8 __attribute__((ext_vector_type(8)));
typedef u16 u16x8 __attribute__((ext_vector_type(8)));
typedef u32 u32x4 __attribute__((ext_vector_type(4)));

__device__ __forceinline__ u16 f2bf(float f) {
    return __builtin_bit_cast(u16, static_cast<__bf16>(f));
}

// ---------------------------------------------------------------------------
// W pack: [Wk|Wq|Wv] f32 -> bf16 in MFMA B-fragment order (unchanged).
// ---------------------------------------------------------------------------
__global__ __launch_bounds__(256) void wpack_kernel(
    const float* __restrict__ Wk, const float* __restrict__ Wq,
    const float* __restrict__ Wv, u16* __restrict__ wp)
{
    int slot = blockIdx.x * 256 + threadIdx.x;   // 0..24575
    int n16  = slot >> 11;
    int rem  = slot & 2047;
    int kc   = rem >> 6;
    int lane = rem & 63;
    int l15 = lane & 15, lg = lane >> 4;
    int col = n16 * 16 + l15;                    // 0..191
    const float* __restrict__ Wm = (col < 64) ? Wk : (col < 128) ? Wq : Wv;
    float sc = (col >= 64 && col < 128) ? 0.03125f : 1.0f;
    const float* src = &Wm[(size_t)(col & 63) * Cn + kc * 32 + lg * 8];
    float4 lo = *reinterpret_cast<const float4*>(src);
    float4 hi = *reinterpret_cast<const float4*>(src + 4);
    u16x8 o;
    o[0] = f2bf(lo.x * sc); o[1] = f2bf(lo.y * sc);
    o[2] = f2bf(lo.z * sc); o[3] = f2bf(lo.w * sc);
    o[4] = f2bf(hi.x * sc); o[5] = f2bf(hi.y * sc);
    o[6] = f2bf(hi.z * sc); o[7] = f2bf(hi.w * sc);
    *reinterpret_cast<u16x8*>(&wp[(size_t)slot * 8]) = o;
}

// ---------------------------------------------------------------------------
// QKV projection: R14-exact (BM=32, 256 threads).
// ---------------------------------------------------------------------------
__global__ __launch_bounds__(256) void qkv_proj(
    const float* __restrict__ x, const u16* __restrict__ wp,
    u16* __restrict__ kb, u16* __restrict__ qb, u16* __restrict__ vb)
{
    __shared__ float xs[2][32 * 68];

    const int tid  = threadIdx.x;
    const int lane = tid & 63;
    const int w    = tid >> 6;        // 0..3
    const int rg   = w & 1;           // rowgroup of 16
    const int cg   = w >> 1;          // colgroup of 96 (6 tiles)
    const int l15  = lane & 15;
    const int lg   = lane >> 4;

    const int row0 = blockIdx.x * 32;
    const int sr   = tid >> 4;          // 0..15
    const int scc  = (tid & 15) << 2;

    f32x4 acc[6];
#pragma unroll
    for (int nt = 0; nt < 6; ++nt)
#pragma unroll
        for (int r = 0; r < 4; ++r) acc[nt][r] = 0.f;

    const float* __restrict__ xsrc0 = &x[(size_t)(row0 + sr) * Cn + scc];
    const float* __restrict__ xsrc1 = &x[(size_t)(row0 + sr + 16) * Cn + scc];
    const u16* __restrict__ wbase = wp + (size_t)cg * 6 * 32 * 64 * 8;

    float4 ga = *reinterpret_cast<const float4*>(xsrc0);
    float4 gb = *reinterpret_cast<const float4*>(xsrc1);
    *reinterpret_cast<float4*>(&xs[0][sr * 68 + scc]) = ga;
    *reinterpret_cast<float4*>(&xs[0][(sr + 16) * 68 + scc]) = gb;
    __syncthreads();

    for (int ks = 0; ks < 16; ++ks) {
        const int cur = ks & 1;
        if (ks < 15) {
            ga = *reinterpret_cast<const float4*>(xsrc0 + (ks + 1) * 64);
            gb = *reinterpret_cast<const float4*>(xsrc1 + (ks + 1) * 64);
        }
#pragma unroll
        for (int kc2 = 0; kc2 < 2; ++kc2) {
            const float* ap = &xs[cur][(rg * 16 + l15) * 68 + kc2 * 32 + (lg << 3)];
            f32x4 a0 = *reinterpret_cast<const f32x4*>(ap);
            f32x4 a1 = *reinterpret_cast<const f32x4*>(ap + 4);
            bf16x8 a;
            a[0] = (__bf16)a0[0]; a[1] = (__bf16)a0[1];
            a[2] = (__bf16)a0[2]; a[3] = (__bf16)a0[3];
            a[4] = (__bf16)a1[0]; a[5] = (__bf16)a1[1];
            a[6] = (__bf16)a1[2]; a[7] = (__bf16)a1[3];
            const int kcg = ks * 2 + kc2;
#pragma unroll
            for (int nt = 0; nt < 6; ++nt) {
                bf16x8 bfr = *reinterpret_cast<const bf16x8*>(
                    &wbase[(size_t)((nt * 32 + kcg) * 64 + lane) * 8]);
                acc[nt] = __builtin_amdgcn_mfma_f32_16x16x32_bf16(a, bfr, acc[nt], 0, 0, 0);
            }
        }
        if (ks < 15) {
            *reinterpret_cast<float4*>(&xs[cur ^ 1][sr * 68 + scc]) = ga;
            *reinterpret_cast<float4*>(&xs[cur ^ 1][(sr + 16) * 68 + scc]) = gb;
        }
        __syncthreads();
    }

#pragma unroll
    for (int nt = 0; nt < 6; ++nt) {
        const int col0 = cg * 96 + nt * 16;
        const int mat  = col0 >> 6;
        u16* __restrict__ ob = (mat == 0) ? kb : (mat == 1) ? qb : vb;
        const int h = (col0 & 63) + l15;
#pragma unroll
        for (int reg = 0; reg < 4; ++reg) {
            const int grow = row0 + rg * 16 + (lg << 2) + reg;
            ob[(size_t)grow * Hn + h] = f2bf(acc[nt][reg]);
        }
    }
}

// ---------------------------------------------------------------------------
// Causal flash attention, split-KV 512-key chunks, swapped QK^T (R14-exact)
// + T1 XCD-aware block swizzle: swz = (bid%8)*80 + bid/8 (640%8==0, exact)
// -> each XCD gets a contiguous run of 80 work items (half a batch), so its
// L2 holds ~2MB of KV instead of interleaving all 4 batches.
// ---------------------------------------------------------------------------
__global__ __launch_bounds__(256) void attn(
    const u16* __restrict__ qb, const u16* __restrict__ kb,
    const u16* __restrict__ vb, float* __restrict__ Opart,
    float* __restrict__ mlb, float* __restrict__ out)
{
    __shared__ u16 Ks[2][64 * 72];
    __shared__ u16 VTs[2][64 * 72];

    const int tid  = threadIdx.x;
    const int lane = tid & 63;
    const int w    = tid >> 6;
    const int g    = w >> 1;
    const int p    = w & 1;
    const int l15  = lane & 15;
    const int lg   = lane >> 4;

    // T1 XCD swizzle (bijective: 640 = 8 * 80)
    const int bid = (blockIdx.x & 7) * 80 + (blockIdx.x >> 3);
    const int b = bid / 160;
    const int r = bid % 160;
    int gq = 3;
    while (8 * gq * (gq + 1) > r) --gq;
    const int rr = r - 8 * gq * (gq + 1);
    const int qt = gq * 16 + rr / (gq + 1);
    const int c  = rr % (gq + 1);
    const int c8 = c * 8;

    const int t0  = qt * 32;
    const int wr0 = t0 + g * 16;
    const int nkt = (qt >> 1) + 1;
    const int rounds = (nkt - c8 + 1) >> 1 < 4 ? (nkt - c8 + 1) >> 1 : 4;
    const size_t kvbase = (size_t)b * Tn * Hn;

    bf16x8 qf[2];
    {
        const u16* qrow = qb + ((size_t)(b * Tn + wr0 + l15)) * Hn;
        qf[0] = *reinterpret_cast<const bf16x8*>(&qrow[(lg << 3)]);
        qf[1] = *reinterpret_cast<const bf16x8*>(&qrow[32 + (lg << 3)]);
    }

    f32x4 o[4];
    float m = -INFINITY, ls = 0.f;
#pragma unroll
    for (int nt = 0; nt < 4; ++nt)
#pragma unroll
        for (int rg2 = 0; rg2 < 4; ++rg2) o[nt][rg2] = 0.f;

    const int srcA = l15 + ((lane >> 4) & 1) * 32;
    const int srcB = srcA + 16;
    const bool hiSel = ((lg >> 1) & 1) != 0;

    for (int s = 0; s < rounds; ++s) {
        const int kt0 = c8 + 2 * s, kt1 = kt0 + 1;
        {
#pragma unroll
            for (int i = 0; i < 2; ++i) {
                int cc = tid + 256 * i;
                int rr2 = cc >> 3, cb = (cc & 7) << 3;
                *reinterpret_cast<u16x8*>(&Ks[0][rr2 * 72 + cb]) =
                    *reinterpret_cast<const u16x8*>(&kb[kvbase + (size_t)(kt0 * 64 + rr2) * Hn + cb]);
            }
#pragma unroll
            for (int i = 0; i < 2; ++i) {
                int cc = tid + 256 * i;
                int k = cc & 63, d0 = (cc >> 6) << 3;
                u16x8 v = *reinterpret_cast<const u16x8*>(&vb[kvbase + (size_t)(kt0 * 64 + k) * Hn + d0]);
#pragma unroll
                for (int j = 0; j < 8; ++j) VTs[0][(d0 + j) * 72 + k] = v[j];
            }
        }
        if (kt1 < nkt) {
#pragma unroll
            for (int i = 0; i < 2; ++i) {
                int cc = tid + 256 * i;
                int rr2 = cc >> 3, cb = (cc & 7) << 3;
                *reinterpret_cast<u16x8*>(&Ks[1][rr2 * 72 + cb]) =
                    *reinterpret_cast<const u16x8*>(&kb[kvbase + (size_t)(kt1 * 64 + rr2) * Hn + cb]);
            }
#pragma unroll
            for (int i = 0; i < 2; ++i) {
                int cc = tid + 256 * i;
                int k = cc & 63, d0 = (cc >> 6) << 3;
                u16x8 v = *reinterpret_cast<const u16x8*>(&vb[kvbase + (size_t)(kt1 * 64 + k) * Hn + d0]);
#pragma unroll
                for (int j = 0; j < 8; ++j) VTs[1][(d0 + j) * 72 + k] = v[j];
            }
        }
        __syncthreads();

        const int mykt = kt0 + p;
        if (mykt < nkt) {
            f32x4 sf[4];
#pragma unroll
            for (int nt = 0; nt < 4; ++nt)
#pragma unroll
                for (int rg2 = 0; rg2 < 4; ++rg2) sf[nt][rg2] = 0.f;
#pragma unroll
            for (int kc = 0; kc < 2; ++kc) {
#pragma unroll
                for (int nt = 0; nt < 4; ++nt) {
                    bf16x8 kf = *reinterpret_cast<const bf16x8*>(
                        &Ks[p][(nt * 16 + l15) * 72 + kc * 32 + (lg << 3)]);
                    sf[nt] = __builtin_amdgcn_mfma_f32_16x16x32_bf16(kf, qf[kc], sf[nt], 0, 0, 0);
                }
            }
            if (mykt * 64 + 63 > wr0) {
                const int tq = wr0 + l15;
#pragma unroll
                for (int nt = 0; nt < 4; ++nt) {
#pragma unroll
                    for (int reg = 0; reg < 4; ++reg) {
                        int kg = mykt * 64 + nt * 16 + (lg << 2) + reg;
                        if (kg > tq) sf[nt][reg] = -INFINITY;
                    }
                }
            }
            float tm = sf[0][0];
#pragma unroll
            for (int nt = 0; nt < 4; ++nt)
#pragma unroll
                for (int reg = 0; reg < 4; ++reg) tm = fmaxf(tm, sf[nt][reg]);
            tm = fmaxf(tm, __shfl_xor(tm, 16, 64));
            tm = fmaxf(tm, __shfl_xor(tm, 32, 64));
            if (!__all((tm <= m + 8.f) ? 1 : 0)) {
                float nm = fmaxf(m, tm);
                float al = __expf(m - nm);
                ls *= al;
                float alo[4];
#pragma unroll
                for (int reg = 0; reg < 4; ++reg)
                    alo[reg] = __shfl(al, (lg << 2) | reg, 64);
#pragma unroll
                for (int nt = 0; nt < 4; ++nt)
#pragma unroll
                    for (int reg = 0; reg < 4; ++reg) o[nt][reg] *= alo[reg];
                m = nm;
            }
            float pvv[4][4];
            float rs = 0.f;
#pragma unroll
            for (int nt = 0; nt < 4; ++nt)
#pragma unroll
                for (int reg = 0; reg < 4; ++reg) {
                    pvv[nt][reg] = __expf(sf[nt][reg] - m);
                    rs += pvv[nt][reg];
                }
            rs += __shfl_xor(rs, 16, 64);
            rs += __shfl_xor(rs, 32, 64);
            ls += rs;
            u32 wv[4][2];
#pragma unroll
            for (int nt = 0; nt < 4; ++nt)
#pragma unroll
                for (int h = 0; h < 2; ++h)
                    wv[nt][h] = (u32)f2bf(pvv[nt][2 * h]) |
                                ((u32)f2bf(pvv[nt][2 * h + 1]) << 16);
            bf16x8 pa[2];
#pragma unroll
            for (int kc = 0; kc < 2; ++kc) {
                u32 a0 = __shfl(wv[kc * 2][0], srcA, 64);
                u32 b0 = __shfl(wv[kc * 2 + 1][0], srcA, 64);
                u32 a1 = __shfl(wv[kc * 2][1], srcA, 64);
                u32 b1 = __shfl(wv[kc * 2 + 1][1], srcA, 64);
                u32 a2 = __shfl(wv[kc * 2][0], srcB, 64);
                u32 b2 = __shfl(wv[kc * 2 + 1][0], srcB, 64);
                u32 a3 = __shfl(wv[kc * 2][1], srcB, 64);
                u32 b3 = __shfl(wv[kc * 2 + 1][1], srcB, 64);
                u32x4 pw;
                pw[0] = hiSel ? b0 : a0;
                pw[1] = hiSel ? b1 : a1;
                pw[2] = hiSel ? b2 : a2;
                pw[3] = hiSel ? b3 : a3;
                pa[kc] = __builtin_bit_cast(bf16x8, pw);
            }
#pragma unroll
            for (int kc = 0; kc < 2; ++kc) {
#pragma unroll
                for (int nt = 0; nt < 4; ++nt) {
                    bf16x8 vf = *reinterpret_cast<const bf16x8*>(
                        &VTs[p][(nt * 16 + l15) * 72 + kc * 32 + (lg << 3)]);
                    o[nt] = __builtin_amdgcn_mfma_f32_16x16x32_bf16(pa[kc], vf, o[nt], 0, 0, 0);
                }
            }
        }
        __syncthreads();
    }

    float* slab = reinterpret_cast<float*>(&Ks[0][0]);
    float* sb = slab + g * (24 * 64);
    if (p == 1) {
#pragma unroll
        for (int nt = 0; nt < 4; ++nt)
#pragma unroll
            for (int reg = 0; reg < 4; ++reg)
                sb[(nt * 4 + reg) * 64 + lane] = o[nt][reg];
        if (lane < 16) {
            sb[1024 + lane] = m;
            sb[1040 + lane] = ls;
        }
    }
    __syncthreads();
    if (p == 0) {
        float mA[4], lA[4], mB[4], lB[4];
#pragma unroll
        for (int reg = 0; reg < 4; ++reg) {
            int q = (lg << 2) | reg;
            mA[reg] = __shfl(m, q, 64);
            lA[reg] = __shfl(ls, q, 64);
            mB[reg] = sb[1024 + q];
            lB[reg] = sb[1040 + q];
        }
        if (gq == 0) {
#pragma unroll
            for (int reg = 0; reg < 4; ++reg) {
                float ms = fmaxf(mA[reg], mB[reg]);
                float aA = __expf(mA[reg] - ms);
                float aB = __expf(mB[reg] - ms);
                float inv = 1.0f / (aA * lA[reg] + aB * lB[reg]);
                int grow = t0 + g * 16 + (lg << 2) + reg;
                float* orow = out + ((size_t)(b * Tn) + grow) * Hn;
#pragma unroll
                for (int nt = 0; nt < 4; ++nt)
                    orow[nt * 16 + l15] =
                        (aA * o[nt][reg] + aB * sb[(nt * 4 + reg) * 64 + lane]) * inv;
            }
        } else {
            const size_t pidx = (size_t)(b * 64 + qt) * 4 + c;
            float* __restrict__ ob = Opart + pidx * 2048;
#pragma unroll
            for (int reg = 0; reg < 4; ++reg) {
                float ms = fmaxf(mA[reg], mB[reg]);
                float aA = __expf(mA[reg] - ms);
                float aB = __expf(mB[reg] - ms);
                int row32 = g * 16 + (lg << 2) + reg;
                if (l15 == 0) {
                    float* mlp = mlb + pidx * 64 + row32 * 2;
                    mlp[0] = ms;
                    mlp[1] = aA * lA[reg] + aB * lB[reg];
                }
#pragma unroll
                for (int nt = 0; nt < 4; ++nt)
                    ob[row32 * 64 + nt * 16 + l15] =
                        aA * o[nt][reg] + aB * sb[(nt * 4 + reg) * 64 + lane];
            }
        }
    }
}

// ---------------------------------------------------------------------------
// Combine KV-chunk partials (qt >= 16 only; <=4 chunks).  grid 192.
// ---------------------------------------------------------------------------
__global__ __launch_bounds__(256) void attn_merge(
    const float* __restrict__ Opart, const float* __restrict__ mlb,
    float* __restrict__ out)
{
    const int bid = blockIdx.x;
    const int b  = bid / 48;
    const int qt = 16 + bid % 48;
    const int nch = (qt >> 4) + 1;               // 2..4
    const int t = threadIdx.x;
    const int row = t >> 3, d0 = (t & 7) << 3;
    const size_t pbase = (size_t)(b * 64 + qt) * 4;

    float mc[4], lc[4];
#pragma unroll
    for (int cc = 0; cc < 4; ++cc) {
        if (cc < nch) {
            const float* mlp = mlb + (pbase + cc) * 64 + row * 2;
            mc[cc] = mlp[0];
            lc[cc] = mlp[1];
        } else { mc[cc] = -INFINITY; lc[cc] = 0.f; }
    }
    float mfin = fmaxf(fmaxf(mc[0], mc[1]), fmaxf(mc[2], mc[3]));

    float wgt[4], l = 0.f;
#pragma unroll
    for (int cc = 0; cc < 4; ++cc) {
        wgt[cc] = (cc < nch) ? __expf(mc[cc] - mfin) : 0.f;
        l += lc[cc] * wgt[cc];
    }

    f32x4 O0 = {0.f, 0.f, 0.f, 0.f}, O1 = {0.f, 0.f, 0.f, 0.f};
#pragma unroll
    for (int cc = 0; cc < 4; ++cc) {
        if (cc < nch) {
            const float* op = Opart + (pbase + cc) * 2048 + row * 64 + d0;
            f32x4 c0 = *reinterpret_cast<const f32x4*>(op);
            f32x4 c1 = *reinterpret_cast<const f32x4*>(op + 4);
            O0 += c0 * wgt[cc];
            O1 += c1 * wgt[cc];
        }
    }
    float inv = 1.f / l;
    float* orow = out + ((size_t)(b * Tn + qt * 32 + row)) * Hn + d0;
    *reinterpret_cast<f32x4*>(orow)     = O0 * inv;
    *reinterpret_cast<f32x4*>(orow + 4) = O1 * inv;
}

extern "C" void kernel_launch(void* const* d_in, const int* in_sizes, int n_in,
                              void* d_out, int out_size, void* d_ws, size_t ws_size,
                              hipStream_t stream) {
    const float* x  = (const float*)d_in[0];
    const float* Wk = (const float*)d_in[1];
    const float* Wq = (const float*)d_in[2];
    const float* Wv = (const float*)d_in[3];
    float* out = (float*)d_out;

    const size_t rows = (size_t)4 * Tn;            // 8192
    u16* kbuf = (u16*)d_ws;                        // [8192][64] bf16
    u16* qbuf = kbuf + rows * Hn;
    u16* vbuf = qbuf + rows * Hn;
    u16* wpk  = vbuf + rows * Hn;                  // 196608 u16
    float* Opart = (float*)(wpk + 196608);         // [256][4][32][64] f32
    float* mlb   = Opart + (size_t)256 * 4 * 2048; // [256][4][32][2] f32

    wpack_kernel<<<96, 256, 0, stream>>>(Wk, Wq, Wv, wpk);
    qkv_proj<<<256, 256, 0, stream>>>(x, wpk, kbuf, qbuf, vbuf);
    attn<<<640, 256, 0, stream>>>(qbuf, kbuf, vbuf, Opart, mlb, out);
    attn_merge<<<192, 256, 0, stream>>>(Opart, mlb, out);
}